// Round 10
// baseline (231.420 us; speedup 1.0000x reference)
//
#include <hip/hip_runtime.h>
#include <hip/hip_bf16.h>

#define HIDDEN 1024
#define NHEADS 16
#define HEADD  64
#define BATCH  8
#define SEQ    1024
#define MROWS  (BATCH*SEQ)   // 8192

typedef __bf16 bf16x8 __attribute__((ext_vector_type(8)));
typedef float  floatx4 __attribute__((ext_vector_type(4)));
typedef unsigned short ushort8_t __attribute__((ext_vector_type(8)));
typedef _Float16 f16x4 __attribute__((ext_vector_type(4)));
typedef _Float16 f16x2 __attribute__((ext_vector_type(2)));
typedef const __attribute__((address_space(1))) unsigned int* gas_u32p;
typedef __attribute__((address_space(3))) unsigned int* las_u32p;

__device__ __forceinline__ unsigned short f2bf(float f) {
  __hip_bfloat16 h = __float2bfloat16(f);
  return __builtin_bit_cast(unsigned short, h);
}

__device__ __forceinline__ bf16x8 ld_bf8(const unsigned short* p) {
  ushort8_t u = *(const ushort8_t*)p;
  return __builtin_bit_cast(bf16x8, u);
}

__device__ __forceinline__ f16x2 pk_f16(float a, float b) {
  return __builtin_bit_cast(f16x2, __builtin_amdgcn_cvt_pkrtz(a, b));
}

__device__ __forceinline__ void gload_lds16(const void* g, void* l) {
  __builtin_amdgcn_global_load_lds((gas_u32p)g, (las_u32p)l, 16, 0, 0);
}

// ---------------------------------------------------------------- merged prep:
// blocks [0,1024): transpose+cast weights [K][N] f32 -> [N][K] bf16
// blocks [1024,3072): cast x f32 -> bf16, 4 float4 per thread (was 8192 4KB blocks —
// fewer dispatch rounds, more per-thread ILP on a pure-BW path)
__global__ __launch_bounds__(256) void prep_kernel(
    const float* __restrict__ x,
    const float* __restrict__ w0, const float* __restrict__ w1,
    const float* __restrict__ w2, const float* __restrict__ w3,
    unsigned short* __restrict__ xb,
    unsigned short* __restrict__ o0, unsigned short* __restrict__ o1,
    unsigned short* __restrict__ o2, unsigned short* __restrict__ o3) {
  __shared__ __align__(16) unsigned short tile[64 * 68];
  const int bid = blockIdx.x;
  const int tid = threadIdx.x;
  if (bid >= 1024) {                 // ---- cast x: 4 coalesced float4 per thread
    int base = (bid - 1024) * 1024 + tid;
#pragma unroll
    for (int it = 0; it < 4; ++it) {
      int i = base + it * 256;
      float4 v = ((const float4*)x)[i];
      ushort4 o = make_ushort4(f2bf(v.x), f2bf(v.y), f2bf(v.z), f2bf(v.w));
      ((ushort4*)xb)[i] = o;
    }
    return;
  }
  // ---- transpose+cast one 64x64 tile of one weight
  const int z = bid >> 8;                  // which weight
  const int k0 = (bid & 15) * 64, n0 = ((bid >> 4) & 15) * 64;
  const float* src = (z == 0) ? w0 : (z == 1) ? w1 : (z == 2) ? w2 : w3;
  unsigned short* dst = (z == 0) ? o0 : (z == 1) ? o1 : (z == 2) ? o2 : o3;
#pragma unroll
  for (int it = 0; it < 4; ++it) {
    int c = tid + 256 * it;
    int row = c >> 4, f4 = c & 15;
    float4 v = *(const float4*)(src + (size_t)(k0 + row) * HIDDEN + n0 + 4 * f4);
    ushort4 u = make_ushort4(f2bf(v.x), f2bf(v.y), f2bf(v.z), f2bf(v.w));
    *(ushort4*)(&tile[row * 68 + 4 * f4]) = u;
  }
  __syncthreads();
#pragma unroll
  for (int it = 0; it < 2; ++it) {
    int c = tid + 256 * it;
    int nrow = c >> 3, kc = (c & 7) * 8;
    ushort8_t u;
#pragma unroll
    for (int j = 0; j < 8; ++j) u[j] = tile[(kc + j) * 68 + nrow];
    *(ushort8_t*)(dst + (size_t)(n0 + nrow) * HIDDEN + k0 + kc) = u;
  }
}

// ================================================================ shared sync helpers
#define BAR __builtin_amdgcn_s_barrier()
#define WLG do { asm volatile("s_waitcnt lgkmcnt(0)" ::: "memory"); \
                 __builtin_amdgcn_sched_barrier(0); } while (0)
#define WVM(n) asm volatile("s_waitcnt vmcnt(" #n ")" ::: "memory")

template <int N> __device__ __forceinline__ void wvm() {
  if constexpr (N == 0)      asm volatile("s_waitcnt vmcnt(0)" ::: "memory");
  else if constexpr (N == 2) asm volatile("s_waitcnt vmcnt(2)" ::: "memory");
  else if constexpr (N == 3) asm volatile("s_waitcnt vmcnt(3)" ::: "memory");
}

// ================================================================ qkv body: BK=32 dbuf, 48 KiB
// VERBATIM round-3 macro body (measured 64.6-66.2 us, refcheck'd x4 rounds). LESSON (r5): a
// lambda/template re-expression of this exact schedule cost +13% — keep this codegen.
// LESSON (r4,r7): unified VGPR/AGPR file — a launch-bounds cap of C gives ~C/2 arch VGPRs +
// C/2 AGPRs; the live set must clear THAT split. (512,4): cap 128 = 64 VGPR + 64 AGPR acc ✓.
// Occupancy note (r9): VGPR (128/wave) caps residency at 2 blocks/CU (LDS would allow 3).
#define LDSA2(buf) ((buf) * 24576)
#define LDSB2(buf) ((buf) * 24576 + 8192)

#define RDP2(buf) do {                                                             \
    _Pragma("unroll") for (int m_ = 0; m_ < 4; ++m_)                               \
      af[m_] = *(const bf16x8*)(ldsb + LDSA2(buf) +                                \
                                (wm * 64 + 16 * m_ + lr) * 64 + colx);             \
    _Pragma("unroll") for (int n_ = 0; n_ < 4; ++n_)                               \
      bc[n_] = *(const bf16x8*)(ldsb + LDSB2(buf) +                                \
                                (wn * 64 + 16 * n_ + lr) * 64 + colx);             \
  } while (0)

#define MM2 do {                                                                   \
    __builtin_amdgcn_s_setprio(1);                                                 \
    _Pragma("unroll") for (int m_ = 0; m_ < 4; ++m_)                               \
      _Pragma("unroll") for (int n_ = 0; n_ < 4; ++n_)                             \
        acc[m_][n_] = __builtin_amdgcn_mfma_f32_16x16x32_bf16(                     \
            af[m_], bc[n_], acc[m_][n_], 0, 0, 0);                                 \
    __builtin_amdgcn_s_setprio(0);                                                 \
  } while (0)

#define STG2(buf, t) do {                                                          \
    int go_ = (t) * 64;                                                            \
    gload_lds16(aS + go_,  ldsb + LDSA2(buf) + tid * 16);                          \
    gload_lds16(bS0 + go_, ldsb + LDSB2(buf) + tid * 16);                          \
    gload_lds16(bS1 + go_, ldsb + LDSB2(buf) + 8192 + tid * 16);                   \
  } while (0)

// OUT: 1 = bf16, 2 = f16 (row-bias, V^T)
template <int OUT>
__device__ __forceinline__ void gemm_qkv32_body(
    const unsigned short* __restrict__ A,   // [>=128][1024] bf16, pre-offset to tile row 0
    const unsigned short* __restrict__ Bt,  // [>=256][1024] bf16, pre-offset to tile n-row 0
    const float* __restrict__ bias,         // col-indexed (OUT==1) or row-indexed (OUT==2)
    char* __restrict__ C, int ldC, float scale,
    char* ldsb) {
  const int tid = threadIdx.x;
  const int lane = tid & 63;
  const int wid = tid >> 6;
  const int wm = wid >> 2, wn = wid & 3;
  const int lr = lane & 15, q = lane >> 4;
  const int colx = (16 * q) ^ (((lr >> 3) & 1) << 5);   // st_16x32 read-side XOR

  // inverse-swizzled global sources (linear LDS dest, rule #21)
  const char *aS, *bS0, *bS1;
  {
    int linA = tid * 16;
    int lgA = linA ^ (((linA >> 9) & 1) << 5);
    aS = (const char*)A + (lgA >> 6) * 2048 + (lgA & 63);
    int linB0 = tid * 16, linB1 = 8192 + tid * 16;
    int lgB0 = linB0 ^ (((linB0 >> 9) & 1) << 5);
    int lgB1 = linB1 ^ (((linB1 >> 9) & 1) << 5);
    bS0 = (const char*)Bt + (lgB0 >> 6) * 2048 + (lgB0 & 63);
    bS1 = (const char*)Bt + (lgB1 >> 6) * 2048 + (lgB1 & 63);
  }

  floatx4 acc[4][4] = {};
  bf16x8 af[4], bc[4];

  STG2(0, 0);                                  // prologue: tile 0 -> buf0
#pragma unroll 1
  for (int i = 0; i < 15; ++i) {
    STG2(1, 2 * i + 1); WVM(3); BAR; RDP2(0); WLG; MM2; BAR;
    STG2(0, 2 * i + 2); WVM(3); BAR; RDP2(1); WLG; MM2; BAR;
  }
  STG2(1, 31); WVM(3); BAR; RDP2(0); WLG; MM2; BAR;
               WVM(0); BAR; RDP2(1); WLG; MM2;

  // epilogue: C/D layout col=lane&15, row=(lane>>4)*4+reg
  float cb[4];
  if constexpr (OUT != 2) {
#pragma unroll
    for (int n_ = 0; n_ < 4; ++n_) cb[n_] = bias[wn * 64 + 16 * n_ + lr];
  }
#pragma unroll
  for (int m_ = 0; m_ < 4; ++m_) {
    int row = wm * 64 + 16 * m_ + q * 4;
    float rb[4];
    if constexpr (OUT == 2) {
      float4 t = *(const float4*)&bias[row];
      rb[0] = t.x; rb[1] = t.y; rb[2] = t.z; rb[3] = t.w;
    }
#pragma unroll
    for (int n_ = 0; n_ < 4; ++n_) {
      int col = wn * 64 + 16 * n_ + lr;
#pragma unroll
      for (int r = 0; r < 4; ++r) {
        float v = (acc[m_][n_][r] + (OUT == 2 ? rb[r] : cb[n_])) * scale;
        int idx = (row + r) * ldC + col;
        if constexpr (OUT == 1) ((unsigned short*)C)[idx] = f2bf(v);
        else                    ((_Float16*)C)[idx] = (_Float16)v;
      }
    }
  }
}

#undef RDP2
#undef MM2
#undef STG2
#undef LDSA2
#undef LDSB2

// ================================================================ out body: 128x128, BK=32 dbuf
template <int OUT, int BN>
__device__ __forceinline__ void gemm_bk32_body(
    const unsigned short* __restrict__ A, const unsigned short* __restrict__ Bt,
    const float* __restrict__ bias, char* __restrict__ C, int ldC, float scale,
    char* ldsb) {
  constexpr int NF = BN / 64;
  constexpr int WNC = BN / 4;
  constexpr int BUFST = 8192 + BN * 64;
  constexpr int NB2 = (BN == 256);
  constexpr int VC = NB2 ? 3 : 2;

  const int tid = threadIdx.x;
  const int lane = tid & 63;
  const int wid = tid >> 6;
  const int wm = wid >> 2, wn = wid & 3;
  const int lr = lane & 15, q = lane >> 4;
  const int colx = (16 * q) ^ (((lr >> 3) & 1) << 5);

  const char *aS, *bS0, *bS1;
  {
    int linA = tid * 16;
    int lgA = linA ^ (((linA >> 9) & 1) << 5);
    aS = (const char*)A + (lgA >> 6) * 2048 + (lgA & 63);
    int linB0 = tid * 16, linB1 = 8192 + tid * 16;
    int lgB0 = linB0 ^ (((linB0 >> 9) & 1) << 5);
    int lgB1 = linB1 ^ (((linB1 >> 9) & 1) << 5);
    bS0 = (const char*)Bt + (lgB0 >> 6) * 2048 + (lgB0 & 63);
    bS1 = (const char*)Bt + (lgB1 >> 6) * 2048 + (lgB1 & 63);
  }

  floatx4 acc[4][NF] = {};
  bf16x8 af[4], bc[NF];

  auto stg = [&](int buf, int t) {
    int go = t * 64;
    char* base = ldsb + buf * BUFST;
    gload_lds16(aS + go,  base + tid * 16);
    gload_lds16(bS0 + go, base + 8192 + tid * 16);
    if constexpr (NB2) gload_lds16(bS1 + go, base + 16384 + tid * 16);
  };
  auto rdp = [&](int buf) {
    char* base = ldsb + buf * BUFST;
#pragma unroll
    for (int m_ = 0; m_ < 4; ++m_)
      af[m_] = *(const bf16x8*)(base + (wm * 64 + 16 * m_ + lr) * 64 + colx);
#pragma unroll
    for (int n_ = 0; n_ < NF; ++n_)
      bc[n_] = *(const bf16x8*)(base + 8192 + (wn * WNC + 16 * n_ + lr) * 64 + colx);
  };
  auto mm = [&]() {
    __builtin_amdgcn_s_setprio(1);
#pragma unroll
    for (int m_ = 0; m_ < 4; ++m_)
#pragma unroll
      for (int n_ = 0; n_ < NF; ++n_)
        acc[m_][n_] = __builtin_amdgcn_mfma_f32_16x16x32_bf16(af[m_], bc[n_], acc[m_][n_], 0, 0, 0);
    __builtin_amdgcn_s_setprio(0);
  };

  stg(0, 0);
#pragma unroll 1
  for (int i = 0; i < 15; ++i) {
    stg(1, 2 * i + 1); wvm<VC>(); BAR; rdp(0); WLG; mm(); BAR;
    stg(0, 2 * i + 2); wvm<VC>(); BAR; rdp(1); WLG; mm(); BAR;
  }
  stg(1, 31); wvm<VC>(); BAR; rdp(0); WLG; mm(); BAR;
              wvm<0>();  BAR; rdp(1); WLG; mm();

  float cb[NF];
#pragma unroll
  for (int n_ = 0; n_ < NF; ++n_) cb[n_] = bias[wn * WNC + 16 * n_ + lr];
#pragma unroll
  for (int m_ = 0; m_ < 4; ++m_) {
    int row = wm * 64 + 16 * m_ + q * 4;
#pragma unroll
    for (int n_ = 0; n_ < NF; ++n_) {
      int col = wn * WNC + 16 * n_ + lr;
#pragma unroll
      for (int r = 0; r < 4; ++r) {
        float v = (acc[m_][n_][r] + cb[n_]) * scale;
        ((float*)C)[(row + r) * ldC + col] = v;
      }
    }
  }
}

// fused QKV, 768 blocks, 48 KiB LDS, (512,4) — proven config (64.8-66.2 us, r3/r9).
__global__ __launch_bounds__(512, 4) void gemm_qkv256_kernel(
    const unsigned short* __restrict__ xb,
    const unsigned short* __restrict__ wqkt,  // [2048][1024]: wq^T then wk^T (adjacent in ws)
    const unsigned short* __restrict__ wvt,
    const float* __restrict__ bq, const float* __restrict__ bk, const float* __restrict__ bv,
    unsigned short* __restrict__ Qb, unsigned short* __restrict__ Kb,
    _Float16* __restrict__ Vtout, float qscale) {
  __shared__ __align__(16) char lds[2 * (8192 + 16384)];  // 48 KiB
  const int bid = blockIdx.x;
  const int x = bid & 7;
  const int j = bid >> 3;
  if (j < 64) {
    int mt = x * 8 + (j & 7);                // [0,64) token-tiles, partitioned per XCD
    int nq = j >> 3;                         // [0,8)
    int m0 = mt * 128, n0 = nq * 256;
    bool isQ = n0 < HIDDEN;
    int nc = isQ ? n0 : n0 - HIDDEN;
    unsigned short* C = (isQ ? Qb : Kb) + (size_t)m0 * HIDDEN + nc;
    gemm_qkv32_body<1>(xb + (size_t)m0 * HIDDEN, wqkt + (size_t)n0 * HIDDEN,
                       (isQ ? bq : bk) + nc, (char*)C, HIDDEN, isQ ? qscale : 1.0f, lds);
  } else {
    int j2 = j - 64;                         // [0,32)
    int m0 = x * 128;                        // d-slab (one per XCD)
    int n0 = j2 * 256;                       // tokens
    gemm_qkv32_body<2>(wvt + (size_t)m0 * HIDDEN, xb + (size_t)n0 * HIDDEN, bv + m0,
                       (char*)(Vtout + (size_t)m0 * MROWS + n0), MROWS, 1.0f, lds);
  }
}

// out-projection: 128x128 tiles -> 512 blocks = 2 blocks/CU co-resident, 32 KiB LDS.
__global__ __launch_bounds__(512, 4) void gemm_out256_kernel(
    const unsigned short* __restrict__ Mg, const unsigned short* __restrict__ wot,
    const float* __restrict__ bo, float* __restrict__ out) {
  __shared__ __align__(16) char lds[2 * (8192 + 8192)];  // 32 KiB
  const int bid = blockIdx.x;
  const int x = bid & 7;
  const int j = bid >> 3;                    // [0,64)
  int mt = x * 8 + (j & 7);                  // [0,64)
  int nt = j >> 3;                           // [0,8)
  int m0 = mt * 128, n0 = nt * 128;
  gemm_bk32_body<0, 128>(Mg + (size_t)m0 * HIDDEN, wot + (size_t)n0 * HIDDEN, bo + n0,
                         (char*)(out + (size_t)m0 * HIDDEN + n0), HIDDEN, 1.0f, lds);
}

#undef BAR
#undef WLG
#undef WVM

// ---------------------------------------------------------------- attention v9 (round-9 PASSING,
// swizzled K/V LDS — SQ_LDS_BANK_CONFLICT 1.57e7 -> ~0, 63.7 -> ~53.4 us). One zero-risk
// reorder this round: issue stage(0,0) BEFORE the 8 Q global loads so the K/V staging stream
// starts first (the loop-top __syncthreads drains all of it regardless; order only affects
// issue overlap).
// Swizzle (16B-chunk granular, key s(row) = (row>>1)&3):
//   staging: LDS dest linear (rule #21); GLOBAL source chunk XOR'd: cs = ((lane&3)^((lane>>3)&3))*8
//   K read:  kx = (Q8 ^ ((l>>1)&3))*8 ; V read: vx = ((4g+Q8) ^ (l&6))*4
// (256,2), 4 waves share staging, no-max softmax, S^T = K.Q^T, PV via 16x16x16f16.
__global__ __launch_bounds__(256, 2) void attn_kernel(
    const unsigned short* __restrict__ Qb,   // [8192][1024] bf16
    const unsigned short* __restrict__ Kb,   // [8192][1024] bf16
    const _Float16* __restrict__ Vtb,        // [1024][8192] f16  (row = h*64+d, col = b*1024+key)
    unsigned short* __restrict__ Og) {       // [8192][1024] bf16
  __shared__ __align__(16) unsigned short Ks[2][2][32 * 32];  // 8 KB
  __shared__ __align__(16) _Float16      Vs[2][64 * 32];      // 8 KB

  const int tid = threadIdx.x;
  const int wid = tid >> 6;          // wave = q-tile within the quad
  const int lane = tid & 63;
  const int l = lane & 15, Q8 = lane >> 4;
  const int id = blockIdx.x;         // [0, 512)
  const int b = id & 7;              // XCD-affinity: batch b's K/V fits one XCD L2
  const int h = (id >> 3) & 15;
  const int qq = id >> 7;            // [0,4): q-quad
  const int q0 = (qq * 4 + wid) * 64;

  const size_t qkbase = ((size_t)b * SEQ) * HIDDEN + (size_t)h * HEADD;

  const unsigned short* kg = Kb + qkbase;
  const _Float16* vg = Vtb + (size_t)(h * HEADD) * MROWS + (size_t)b * SEQ;
  const int r4 = lane >> 2;                   // 0..15 (staged row within 16-row chunk)
  const int cs = ((lane & 3) ^ ((lane >> 3) & 3)) * 8;  // swizzled source chunk (16B units)
  const int sp = wid >> 1, shl = wid & 1;     // this wave's K chunk
  // read-side swizzled offsets (per-thread constants)
  const int kx = (Q8 ^ ((l >> 1) & 3)) * 8;   // K: shorts within 32-short row
  const int vx0 = ((0 + Q8) ^ (l & 6)) * 4;   // V g=0: f16 within 32-f16 row
  const int vx1 = ((4 + Q8) ^ (l & 6)) * 4;   // V g=1

  auto stage = [&](int buf, int key0) {
    gload_lds16(kg + (size_t)(key0 + 16 * shl + r4) * HIDDEN + 32 * sp + cs,
                &Ks[buf][sp][(16 * shl) * 32]);
    gload_lds16((const void*)(vg + (size_t)(16 * wid + r4) * MROWS + key0 + cs),
                (void*)&Vs[buf][(16 * wid) * 32]);
  };

  stage(0, 0);                       // issue K/V staging first (overlaps Q loads below)

  bf16x8 bq[2][4];
#pragma unroll
  for (int nt = 0; nt < 4; ++nt) {
    const unsigned short* qr = Qb + qkbase + (size_t)(q0 + 16 * nt + l) * HIDDEN + Q8 * 8;
    bq[0][nt] = ld_bf8(qr);
    bq[1][nt] = ld_bf8(qr + 32);
  }

  floatx4 oacc[4][4] = {};
  float lsum[4] = {};

  for (int kt = 0; kt < SEQ / 32; ++kt) {
    const int cbuf = kt & 1;
    __syncthreads();
    if (kt + 1 < SEQ / 32) stage(cbuf ^ 1, (kt + 1) * 32);

#pragma unroll
    for (int g = 0; g < 2; ++g) {
      bf16x8 aK0 = ld_bf8(&Ks[cbuf][0][(16 * g + l) * 32 + kx]);
      bf16x8 aK1 = ld_bf8(&Ks[cbuf][1][(16 * g + l) * 32 + kx]);
      floatx4 sT[4] = {};
#pragma unroll
      for (int nt = 0; nt < 4; ++nt) {
        sT[nt] = __builtin_amdgcn_mfma_f32_16x16x32_bf16(aK0, bq[0][nt], sT[nt], 0, 0, 0);
        sT[nt] = __builtin_amdgcn_mfma_f32_16x16x32_bf16(aK1, bq[1][nt], sT[nt], 0, 0, 0);
      }

      f16x4 pf[4];
#pragma unroll
      for (int nt = 0; nt < 4; ++nt) {
        float p0 = __builtin_amdgcn_exp2f(sT[nt][0]);
        float p1 = __builtin_amdgcn_exp2f(sT[nt][1]);
        float p2 = __builtin_amdgcn_exp2f(sT[nt][2]);
        float p3 = __builtin_amdgcn_exp2f(sT[nt][3]);
        lsum[nt] += (p0 + p1) + (p2 + p3);
        f16x2 lo = pk_f16(p0, p1);
        f16x2 hi = pk_f16(p2, p3);
        pf[nt][0] = lo[0]; pf[nt][1] = lo[1]; pf[nt][2] = hi[0]; pf[nt][3] = hi[1];
      }

      const int vx = g ? vx1 : vx0;
#pragma unroll
      for (int dt = 0; dt < 4; ++dt) {
        f16x4 vf = *(const f16x4*)&Vs[cbuf][(16 * dt + l) * 32 + vx];
#pragma unroll
        for (int nt = 0; nt < 4; ++nt)
          oacc[dt][nt] = __builtin_amdgcn_mfma_f32_16x16x16f16(vf, pf[nt], oacc[dt][nt], 0, 0, 0);
      }
    }
  }

  float inv[4];
#pragma unroll
  for (int nt = 0; nt < 4; ++nt) {
    float s = lsum[nt];
    s += __shfl_xor(s, 16);
    s += __shfl_xor(s, 32);
    inv[nt] = 1.0f / s;
  }

#pragma unroll
  for (int nt = 0; nt < 4; ++nt) {
    unsigned short* orow = Og + qkbase + (size_t)(q0 + 16 * nt + l) * HIDDEN + 4 * Q8;
#pragma unroll
    for (int dt = 0; dt < 4; ++dt) {
      ushort4 o = make_ushort4(f2bf(oacc[dt][nt][0] * inv[nt]),
                               f2bf(oacc[dt][nt][1] * inv[nt]),
                               f2bf(oacc[dt][nt][2] * inv[nt]),
                               f2bf(oacc[dt][nt][3] * inv[nt]));
      *(ushort4*)(orow + 16 * dt) = o;
    }
  }
}

// ----------------------------------------------------------------
extern "C" void kernel_launch(void* const* d_in, const int* in_sizes, int n_in,
                              void* d_out, int out_size, void* d_ws, size_t ws_size,
                              hipStream_t stream) {
  const float* x  = (const float*)d_in[0];
  const float* wq = (const float*)d_in[1];
  const float* bq = (const float*)d_in[2];
  const float* wk = (const float*)d_in[3];
  const float* bk = (const float*)d_in[4];
  const float* wv = (const float*)d_in[5];
  const float* bv = (const float*)d_in[6];
  const float* wo = (const float*)d_in[7];
  const float* bo = (const float*)d_in[8];

  char* ws = (char*)d_ws;
  const size_t XB = (size_t)MROWS * HIDDEN * 2;   // 16 MiB
  const size_t WB = (size_t)HIDDEN * HIDDEN * 2;  // 2 MiB
  unsigned short* xb  = (unsigned short*)(ws);
  unsigned short* wqt = (unsigned short*)(ws + XB);            // wq^T | wk^T contiguous
  unsigned short* wkt = (unsigned short*)(ws + XB + WB);
  unsigned short* wvt = (unsigned short*)(ws + XB + 2 * WB);
  unsigned short* wot = (unsigned short*)(ws + XB + 3 * WB);
  unsigned short* Qb  = (unsigned short*)(ws + XB + 4 * WB);
  unsigned short* Kb  = (unsigned short*)(ws + 2 * XB + 4 * WB);
  _Float16*       Vtb = (_Float16*)      (ws + 3 * XB + 4 * WB);
  unsigned short* Mg  = (unsigned short*)(ws + 4 * XB + 4 * WB);

  // 1. merged prep: transpose+cast weights (blocks 0-1023) + cast x (blocks 1024-3071)
  prep_kernel<<<dim3(3072), 256, 0, stream>>>(
      x, wq, wk, wv, wo, xb, wqt, wkt, wvt, wot);

  // 2. fused QKV projections, BK=32 double-buffer (proven macro body).
  //    Q folded with log2(e)/sqrt(1024).
  const float SQSCALE = 1.44269504088896f / 32.0f;
  gemm_qkv256_kernel<<<dim3(768), 512, 0, stream>>>(
      xb, wqt, wvt, bq, bk, bv, Qb, Kb, Vtb, SQSCALE);

  // 3. attention v9 (proven swizzled) with stage-before-Q reorder
  attn_kernel<<<dim3(SEQ / 256 * NHEADS * BATCH), 256, 0, stream>>>(Qb, Kb, Vtb, Mg);

  // 4. output projection -> fp32 d_out, 128x128 tiles, 512 blocks = 2 blocks/CU co-resident
  gemm_out256_kernel<<<dim3(512), 512, 0, stream>>>(Mg, wot, bo, (float*)d_out);
}

// Round 11
// 230.827 us; speedup vs baseline: 1.0026x; 1.0026x over previous
//
#include <hip/hip_runtime.h>
#include <hip/hip_bf16.h>

#define HIDDEN 1024
#define NHEADS 16
#define HEADD  64
#define BATCH  8
#define SEQ    1024
#define MROWS  (BATCH*SEQ)   // 8192

typedef __bf16 bf16x8 __attribute__((ext_vector_type(8)));
typedef float  floatx4 __attribute__((ext_vector_type(4)));
typedef unsigned short ushort8_t __attribute__((ext_vector_type(8)));
typedef _Float16 f16x4 __attribute__((ext_vector_type(4)));
typedef _Float16 f16x2 __attribute__((ext_vector_type(2)));
typedef const __attribute__((address_space(1))) unsigned int* gas_u32p;
typedef __attribute__((address_space(3))) unsigned int* las_u32p;

__device__ __forceinline__ unsigned short f2bf(float f) {
  __hip_bfloat16 h = __float2bfloat16(f);
  return __builtin_bit_cast(unsigned short, h);
}

__device__ __forceinline__ bf16x8 ld_bf8(const unsigned short* p) {
  ushort8_t u = *(const ushort8_t*)p;
  return __builtin_bit_cast(bf16x8, u);
}

__device__ __forceinline__ f16x2 pk_f16(float a, float b) {
  return __builtin_bit_cast(f16x2, __builtin_amdgcn_cvt_pkrtz(a, b));
}

__device__ __forceinline__ void gload_lds16(const void* g, void* l) {
  __builtin_amdgcn_global_load_lds((gas_u32p)g, (las_u32p)l, 16, 0, 0);
}

// ---------------------------------------------------------------- merged prep:
// blocks [0,1024): transpose+cast weights [K][N] f32 -> [N][K] bf16
// blocks [1024,3072): cast x f32 -> bf16, 4 float4 per thread
__global__ __launch_bounds__(256) void prep_kernel(
    const float* __restrict__ x,
    const float* __restrict__ w0, const float* __restrict__ w1,
    const float* __restrict__ w2, const float* __restrict__ w3,
    unsigned short* __restrict__ xb,
    unsigned short* __restrict__ o0, unsigned short* __restrict__ o1,
    unsigned short* __restrict__ o2, unsigned short* __restrict__ o3) {
  __shared__ __align__(16) unsigned short tile[64 * 68];
  const int bid = blockIdx.x;
  const int tid = threadIdx.x;
  if (bid >= 1024) {                 // ---- cast x: 4 coalesced float4 per thread
    int base = (bid - 1024) * 1024 + tid;
#pragma unroll
    for (int it = 0; it < 4; ++it) {
      int i = base + it * 256;
      float4 v = ((const float4*)x)[i];
      ushort4 o = make_ushort4(f2bf(v.x), f2bf(v.y), f2bf(v.z), f2bf(v.w));
      ((ushort4*)xb)[i] = o;
    }
    return;
  }
  // ---- transpose+cast one 64x64 tile of one weight
  const int z = bid >> 8;                  // which weight
  const int k0 = (bid & 15) * 64, n0 = ((bid >> 4) & 15) * 64;
  const float* src = (z == 0) ? w0 : (z == 1) ? w1 : (z == 2) ? w2 : w3;
  unsigned short* dst = (z == 0) ? o0 : (z == 1) ? o1 : (z == 2) ? o2 : o3;
#pragma unroll
  for (int it = 0; it < 4; ++it) {
    int c = tid + 256 * it;
    int row = c >> 4, f4 = c & 15;
    float4 v = *(const float4*)(src + (size_t)(k0 + row) * HIDDEN + n0 + 4 * f4);
    ushort4 u = make_ushort4(f2bf(v.x), f2bf(v.y), f2bf(v.z), f2bf(v.w));
    *(ushort4*)(&tile[row * 68 + 4 * f4]) = u;
  }
  __syncthreads();
#pragma unroll
  for (int it = 0; it < 2; ++it) {
    int c = tid + 256 * it;
    int nrow = c >> 3, kc = (c & 7) * 8;
    ushort8_t u;
#pragma unroll
    for (int j = 0; j < 8; ++j) u[j] = tile[(kc + j) * 68 + nrow];
    *(ushort8_t*)(dst + (size_t)(n0 + nrow) * HIDDEN + k0 + kc) = u;
  }
}

// ================================================================ shared sync helpers
#define BAR __builtin_amdgcn_s_barrier()
#define WLG do { asm volatile("s_waitcnt lgkmcnt(0)" ::: "memory"); \
                 __builtin_amdgcn_sched_barrier(0); } while (0)
#define WVM(n) asm volatile("s_waitcnt vmcnt(" #n ")" ::: "memory")

template <int N> __device__ __forceinline__ void wvm() {
  if constexpr (N == 0)      asm volatile("s_waitcnt vmcnt(0)" ::: "memory");
  else if constexpr (N == 2) asm volatile("s_waitcnt vmcnt(2)" ::: "memory");
  else if constexpr (N == 3) asm volatile("s_waitcnt vmcnt(3)" ::: "memory");
}

// ================================================================ qkv body: BK=32 TRIPLE-buffer,
// 72 KiB, depth-2 prefetch. This round's single variable: the proven depth-1 schedule
// (64.6-66.2 us x4 rounds) waited on a stage issued only ~1 phase (~600 cyc) earlier — exposed
// HBM latency. Depth-2: phase t stages tile t+2 into buf (t+2)%3 and vmcnt(6) (2 stages x 3
// loads in flight) waits only tile t -> each stage gets ~2 phases to land. Macro bodies
// (RDP2/MM2/STG2) byte-identical to the proven ones; only rotation + wait constants changed.
// Hazard: stage at phase t writes buf (t+2)%3 == (t-1)%3, whose reads finished at t-1's
// lgkmcnt(0) before t-1's closing BAR; the stage is issued after this wave crossed that BAR.
// LDS 3*24576 = 72 KiB -> still 2 blocks/CU (160/72). (512,4): 64 VGPR + 64 AGPR, no spill.
// LESSON (r4,r7): unified VGPR/AGPR file — launch-bounds cap C gives ~C/2 arch VGPRs; the
// live set must clear THAT split. LESSON (r5): keep this macro codegen verbatim.
#define LDSA2(buf) ((buf) * 24576)
#define LDSB2(buf) ((buf) * 24576 + 8192)

#define RDP2(buf) do {                                                             \
    _Pragma("unroll") for (int m_ = 0; m_ < 4; ++m_)                               \
      af[m_] = *(const bf16x8*)(ldsb + LDSA2(buf) +                                \
                                (wm * 64 + 16 * m_ + lr) * 64 + colx);             \
    _Pragma("unroll") for (int n_ = 0; n_ < 4; ++n_)                               \
      bc[n_] = *(const bf16x8*)(ldsb + LDSB2(buf) +                                \
                                (wn * 64 + 16 * n_ + lr) * 64 + colx);             \
  } while (0)

#define MM2 do {                                                                   \
    __builtin_amdgcn_s_setprio(1);                                                 \
    _Pragma("unroll") for (int m_ = 0; m_ < 4; ++m_)                               \
      _Pragma("unroll") for (int n_ = 0; n_ < 4; ++n_)                             \
        acc[m_][n_] = __builtin_amdgcn_mfma_f32_16x16x32_bf16(                     \
            af[m_], bc[n_], acc[m_][n_], 0, 0, 0);                                 \
    __builtin_amdgcn_s_setprio(0);                                                 \
  } while (0)

#define STG2(buf, t) do {                                                          \
    int go_ = (t) * 64;                                                            \
    gload_lds16(aS + go_,  ldsb + LDSA2(buf) + tid * 16);                          \
    gload_lds16(bS0 + go_, ldsb + LDSB2(buf) + tid * 16);                          \
    gload_lds16(bS1 + go_, ldsb + LDSB2(buf) + 8192 + tid * 16);                   \
  } while (0)

// OUT: 1 = bf16, 2 = f16 (row-bias, V^T)
template <int OUT>
__device__ __forceinline__ void gemm_qkv32_body(
    const unsigned short* __restrict__ A,   // [>=128][1024] bf16, pre-offset to tile row 0
    const unsigned short* __restrict__ Bt,  // [>=256][1024] bf16, pre-offset to tile n-row 0
    const float* __restrict__ bias,         // col-indexed (OUT==1) or row-indexed (OUT==2)
    char* __restrict__ C, int ldC, float scale,
    char* ldsb) {
  const int tid = threadIdx.x;
  const int lane = tid & 63;
  const int wid = tid >> 6;
  const int wm = wid >> 2, wn = wid & 3;
  const int lr = lane & 15, q = lane >> 4;
  const int colx = (16 * q) ^ (((lr >> 3) & 1) << 5);   // st_16x32 read-side XOR

  // inverse-swizzled global sources (linear LDS dest, rule #21)
  const char *aS, *bS0, *bS1;
  {
    int linA = tid * 16;
    int lgA = linA ^ (((linA >> 9) & 1) << 5);
    aS = (const char*)A + (lgA >> 6) * 2048 + (lgA & 63);
    int linB0 = tid * 16, linB1 = 8192 + tid * 16;
    int lgB0 = linB0 ^ (((linB0 >> 9) & 1) << 5);
    int lgB1 = linB1 ^ (((linB1 >> 9) & 1) << 5);
    bS0 = (const char*)Bt + (lgB0 >> 6) * 2048 + (lgB0 & 63);
    bS1 = (const char*)Bt + (lgB1 >> 6) * 2048 + (lgB1 & 63);
  }

  floatx4 acc[4][4] = {};
  bf16x8 af[4], bc[4];

  STG2(0, 0); STG2(1, 1);                      // prologue: tiles 0,1 -> bufs 0,1 (depth 2)
#pragma unroll 1
  for (int i = 0; i < 10; ++i) {               // phases t = 3i, 3i+1, 3i+2  (t = 0..29)
    STG2(2, 3 * i + 2); WVM(6); BAR; RDP2(0); WLG; MM2; BAR;
    STG2(0, 3 * i + 3); WVM(6); BAR; RDP2(1); WLG; MM2; BAR;
    STG2(1, 3 * i + 4); WVM(6); BAR; RDP2(2); WLG; MM2; BAR;
  }
  // tail: tiles 30 (buf0), 31 (buf1) already staged; exact descending waits
  WVM(3); BAR; RDP2(0); WLG; MM2; BAR;
  WVM(0); BAR; RDP2(1); WLG; MM2;

  // epilogue: C/D layout col=lane&15, row=(lane>>4)*4+reg
  float cb[4];
  if constexpr (OUT != 2) {
#pragma unroll
    for (int n_ = 0; n_ < 4; ++n_) cb[n_] = bias[wn * 64 + 16 * n_ + lr];
  }
#pragma unroll
  for (int m_ = 0; m_ < 4; ++m_) {
    int row = wm * 64 + 16 * m_ + q * 4;
    float rb[4];
    if constexpr (OUT == 2) {
      float4 t = *(const float4*)&bias[row];
      rb[0] = t.x; rb[1] = t.y; rb[2] = t.z; rb[3] = t.w;
    }
#pragma unroll
    for (int n_ = 0; n_ < 4; ++n_) {
      int col = wn * 64 + 16 * n_ + lr;
#pragma unroll
      for (int r = 0; r < 4; ++r) {
        float v = (acc[m_][n_][r] + (OUT == 2 ? rb[r] : cb[n_])) * scale;
        int idx = (row + r) * ldC + col;
        if constexpr (OUT == 1) ((unsigned short*)C)[idx] = f2bf(v);
        else                    ((_Float16*)C)[idx] = (_Float16)v;
      }
    }
  }
}

#undef RDP2
#undef MM2
#undef STG2
#undef LDSA2
#undef LDSB2

// ================================================================ out body: 128x128, BK=32 dbuf
template <int OUT, int BN>
__device__ __forceinline__ void gemm_bk32_body(
    const unsigned short* __restrict__ A, const unsigned short* __restrict__ Bt,
    const float* __restrict__ bias, char* __restrict__ C, int ldC, float scale,
    char* ldsb) {
  constexpr int NF = BN / 64;
  constexpr int WNC = BN / 4;
  constexpr int BUFST = 8192 + BN * 64;
  constexpr int NB2 = (BN == 256);
  constexpr int VC = NB2 ? 3 : 2;

  const int tid = threadIdx.x;
  const int lane = tid & 63;
  const int wid = tid >> 6;
  const int wm = wid >> 2, wn = wid & 3;
  const int lr = lane & 15, q = lane >> 4;
  const int colx = (16 * q) ^ (((lr >> 3) & 1) << 5);

  const char *aS, *bS0, *bS1;
  {
    int linA = tid * 16;
    int lgA = linA ^ (((linA >> 9) & 1) << 5);
    aS = (const char*)A + (lgA >> 6) * 2048 + (lgA & 63);
    int linB0 = tid * 16, linB1 = 8192 + tid * 16;
    int lgB0 = linB0 ^ (((linB0 >> 9) & 1) << 5);
    int lgB1 = linB1 ^ (((linB1 >> 9) & 1) << 5);
    bS0 = (const char*)Bt + (lgB0 >> 6) * 2048 + (lgB0 & 63);
    bS1 = (const char*)Bt + (lgB1 >> 6) * 2048 + (lgB1 & 63);
  }

  floatx4 acc[4][NF] = {};
  bf16x8 af[4], bc[NF];

  auto stg = [&](int buf, int t) {
    int go = t * 64;
    char* base = ldsb + buf * BUFST;
    gload_lds16(aS + go,  base + tid * 16);
    gload_lds16(bS0 + go, base + 8192 + tid * 16);
    if constexpr (NB2) gload_lds16(bS1 + go, base + 16384 + tid * 16);
  };
  auto rdp = [&](int buf) {
    char* base = ldsb + buf * BUFST;
#pragma unroll
    for (int m_ = 0; m_ < 4; ++m_)
      af[m_] = *(const bf16x8*)(base + (wm * 64 + 16 * m_ + lr) * 64 + colx);
#pragma unroll
    for (int n_ = 0; n_ < NF; ++n_)
      bc[n_] = *(const bf16x8*)(base + 8192 + (wn * WNC + 16 * n_ + lr) * 64 + colx);
  };
  auto mm = [&]() {
    __builtin_amdgcn_s_setprio(1);
#pragma unroll
    for (int m_ = 0; m_ < 4; ++m_)
#pragma unroll
      for (int n_ = 0; n_ < NF; ++n_)
        acc[m_][n_] = __builtin_amdgcn_mfma_f32_16x16x32_bf16(af[m_], bc[n_], acc[m_][n_], 0, 0, 0);
    __builtin_amdgcn_s_setprio(0);
  };

  stg(0, 0);
#pragma unroll 1
  for (int i = 0; i < 15; ++i) {
    stg(1, 2 * i + 1); wvm<VC>(); BAR; rdp(0); WLG; mm(); BAR;
    stg(0, 2 * i + 2); wvm<VC>(); BAR; rdp(1); WLG; mm(); BAR;
  }
  stg(1, 31); wvm<VC>(); BAR; rdp(0); WLG; mm(); BAR;
              wvm<0>();  BAR; rdp(1); WLG; mm();

  float cb[NF];
#pragma unroll
  for (int n_ = 0; n_ < NF; ++n_) cb[n_] = bias[wn * WNC + 16 * n_ + lr];
#pragma unroll
  for (int m_ = 0; m_ < 4; ++m_) {
    int row = wm * 64 + 16 * m_ + q * 4;
#pragma unroll
    for (int n_ = 0; n_ < NF; ++n_) {
      int col = wn * WNC + 16 * n_ + lr;
#pragma unroll
      for (int r = 0; r < 4; ++r) {
        float v = (acc[m_][n_][r] + cb[n_]) * scale;
        ((float*)C)[(row + r) * ldC + col] = v;
      }
    }
  }
}

// fused QKV, 768 blocks, 72 KiB LDS, (512,4) — triple-buffer depth-2 (this round's variable).
__global__ __launch_bounds__(512, 4) void gemm_qkv256_kernel(
    const unsigned short* __restrict__ xb,
    const unsigned short* __restrict__ wqkt,  // [2048][1024]: wq^T then wk^T (adjacent in ws)
    const unsigned short* __restrict__ wvt,
    const float* __restrict__ bq, const float* __restrict__ bk, const float* __restrict__ bv,
    unsigned short* __restrict__ Qb, unsigned short* __restrict__ Kb,
    _Float16* __restrict__ Vtout, float qscale) {
  __shared__ __align__(16) char lds[3 * 24576];  // 72 KiB -> still 2 blocks/CU
  const int bid = blockIdx.x;
  const int x = bid & 7;
  const int j = bid >> 3;
  if (j < 64) {
    int mt = x * 8 + (j & 7);                // [0,64) token-tiles, partitioned per XCD
    int nq = j >> 3;                         // [0,8)
    int m0 = mt * 128, n0 = nq * 256;
    bool isQ = n0 < HIDDEN;
    int nc = isQ ? n0 : n0 - HIDDEN;
    unsigned short* C = (isQ ? Qb : Kb) + (size_t)m0 * HIDDEN + nc;
    gemm_qkv32_body<1>(xb + (size_t)m0 * HIDDEN, wqkt + (size_t)n0 * HIDDEN,
                       (isQ ? bq : bk) + nc, (char*)C, HIDDEN, isQ ? qscale : 1.0f, lds);
  } else {
    int j2 = j - 64;                         // [0,32)
    int m0 = x * 128;                        // d-slab (one per XCD)
    int n0 = j2 * 256;                       // tokens
    gemm_qkv32_body<2>(wvt + (size_t)m0 * HIDDEN, xb + (size_t)n0 * HIDDEN, bv + m0,
                       (char*)(Vtout + (size_t)m0 * MROWS + n0), MROWS, 1.0f, lds);
  }
}

// out-projection: 128x128 tiles -> 512 blocks = 2 blocks/CU co-resident, 32 KiB LDS.
__global__ __launch_bounds__(512, 4) void gemm_out256_kernel(
    const unsigned short* __restrict__ Mg, const unsigned short* __restrict__ wot,
    const float* __restrict__ bo, float* __restrict__ out) {
  __shared__ __align__(16) char lds[2 * (8192 + 8192)];  // 32 KiB
  const int bid = blockIdx.x;
  const int x = bid & 7;
  const int j = bid >> 3;                    // [0,64)
  int mt = x * 8 + (j & 7);                  // [0,64)
  int nt = j >> 3;                           // [0,8)
  int m0 = mt * 128, n0 = nt * 128;
  gemm_bk32_body<0, 128>(Mg + (size_t)m0 * HIDDEN, wot + (size_t)n0 * HIDDEN, bo + n0,
                         (char*)(out + (size_t)m0 * HIDDEN + n0), HIDDEN, 1.0f, lds);
}

#undef BAR
#undef WLG
#undef WVM

// ---------------------------------------------------------------- attention v9 (round-9/10
// PASSING, frozen): swizzled K/V LDS (conflicts 1.57e7 -> ~0), stage-before-Q issue order,
// (256,2), 4 waves share staging, no-max softmax, S^T = K.Q^T, PV via 16x16x16f16.
__global__ __launch_bounds__(256, 2) void attn_kernel(
    const unsigned short* __restrict__ Qb,   // [8192][1024] bf16
    const unsigned short* __restrict__ Kb,   // [8192][1024] bf16
    const _Float16* __restrict__ Vtb,        // [1024][8192] f16  (row = h*64+d, col = b*1024+key)
    unsigned short* __restrict__ Og) {       // [8192][1024] bf16
  __shared__ __align__(16) unsigned short Ks[2][2][32 * 32];  // 8 KB
  __shared__ __align__(16) _Float16      Vs[2][64 * 32];      // 8 KB

  const int tid = threadIdx.x;
  const int wid = tid >> 6;          // wave = q-tile within the quad
  const int lane = tid & 63;
  const int l = lane & 15, Q8 = lane >> 4;
  const int id = blockIdx.x;         // [0, 512)
  const int b = id & 7;              // XCD-affinity: batch b's K/V fits one XCD L2
  const int h = (id >> 3) & 15;
  const int qq = id >> 7;            // [0,4): q-quad
  const int q0 = (qq * 4 + wid) * 64;

  const size_t qkbase = ((size_t)b * SEQ) * HIDDEN + (size_t)h * HEADD;

  const unsigned short* kg = Kb + qkbase;
  const _Float16* vg = Vtb + (size_t)(h * HEADD) * MROWS + (size_t)b * SEQ;
  const int r4 = lane >> 2;                   // 0..15 (staged row within 16-row chunk)
  const int cs = ((lane & 3) ^ ((lane >> 3) & 3)) * 8;  // swizzled source chunk (16B units)
  const int sp = wid >> 1, shl = wid & 1;     // this wave's K chunk
  // read-side swizzled offsets (per-thread constants)
  const int kx = (Q8 ^ ((l >> 1) & 3)) * 8;   // K: shorts within 32-short row
  const int vx0 = ((0 + Q8) ^ (l & 6)) * 4;   // V g=0: f16 within 32-f16 row
  const int vx1 = ((4 + Q8) ^ (l & 6)) * 4;   // V g=1

  auto stage = [&](int buf, int key0) {
    gload_lds16(kg + (size_t)(key0 + 16 * shl + r4) * HIDDEN + 32 * sp + cs,
                &Ks[buf][sp][(16 * shl) * 32]);
    gload_lds16((const void*)(vg + (size_t)(16 * wid + r4) * MROWS + key0 + cs),
                (void*)&Vs[buf][(16 * wid) * 32]);
  };

  stage(0, 0);                       // issue K/V staging first (overlaps Q loads below)

  bf16x8 bq[2][4];
#pragma unroll
  for (int nt = 0; nt < 4; ++nt) {
    const unsigned short* qr = Qb + qkbase + (size_t)(q0 + 16 * nt + l) * HIDDEN + Q8 * 8;
    bq[0][nt] = ld_bf8(qr);
    bq[1][nt] = ld_bf8(qr + 32);
  }

  floatx4 oacc[4][4] = {};
  float lsum[4] = {};

  for (int kt = 0; kt < SEQ / 32; ++kt) {
    const int cbuf = kt & 1;
    __syncthreads();
    if (kt + 1 < SEQ / 32) stage(cbuf ^ 1, (kt + 1) * 32);

#pragma unroll
    for (int g = 0; g < 2; ++g) {
      bf16x8 aK0 = ld_bf8(&Ks[cbuf][0][(16 * g + l) * 32 + kx]);
      bf16x8 aK1 = ld_bf8(&Ks[cbuf][1][(16 * g + l) * 32 + kx]);
      floatx4 sT[4] = {};
#pragma unroll
      for (int nt = 0; nt < 4; ++nt) {
        sT[nt] = __builtin_amdgcn_mfma_f32_16x16x32_bf16(aK0, bq[0][nt], sT[nt], 0, 0, 0);
        sT[nt] = __builtin_amdgcn_mfma_f32_16x16x32_bf16(aK1, bq[1][nt], sT[nt], 0, 0, 0);
      }

      f16x4 pf[4];
#pragma unroll
      for (int nt = 0; nt < 4; ++nt) {
        float p0 = __builtin_amdgcn_exp2f(sT[nt][0]);
        float p1 = __builtin_amdgcn_exp2f(sT[nt][1]);
        float p2 = __builtin_amdgcn_exp2f(sT[nt][2]);
        float p3 = __builtin_amdgcn_exp2f(sT[nt][3]);
        lsum[nt] += (p0 + p1) + (p2 + p3);
        f16x2 lo = pk_f16(p0, p1);
        f16x2 hi = pk_f16(p2, p3);
        pf[nt][0] = lo[0]; pf[nt][1] = lo[1]; pf[nt][2] = hi[0]; pf[nt][3] = hi[1];
      }

      const int vx = g ? vx1 : vx0;
#pragma unroll
      for (int dt = 0; dt < 4; ++dt) {
        f16x4 vf = *(const f16x4*)&Vs[cbuf][(16 * dt + l) * 32 + vx];
#pragma unroll
        for (int nt = 0; nt < 4; ++nt)
          oacc[dt][nt] = __builtin_amdgcn_mfma_f32_16x16x16f16(vf, pf[nt], oacc[dt][nt], 0, 0, 0);
      }
    }
  }

  float inv[4];
#pragma unroll
  for (int nt = 0; nt < 4; ++nt) {
    float s = lsum[nt];
    s += __shfl_xor(s, 16);
    s += __shfl_xor(s, 32);
    inv[nt] = 1.0f / s;
  }

#pragma unroll
  for (int nt = 0; nt < 4; ++nt) {
    unsigned short* orow = Og + qkbase + (size_t)(q0 + 16 * nt + l) * HIDDEN + 4 * Q8;
#pragma unroll
    for (int dt = 0; dt < 4; ++dt) {
      ushort4 o = make_ushort4(f2bf(oacc[dt][nt][0] * inv[nt]),
                               f2bf(oacc[dt][nt][1] * inv[nt]),
                               f2bf(oacc[dt][nt][2] * inv[nt]),
                               f2bf(oacc[dt][nt][3] * inv[nt]));
      *(ushort4*)(orow + 16 * dt) = o;
    }
  }
}

// ----------------------------------------------------------------
extern "C" void kernel_launch(void* const* d_in, const int* in_sizes, int n_in,
                              void* d_out, int out_size, void* d_ws, size_t ws_size,
                              hipStream_t stream) {
  const float* x  = (const float*)d_in[0];
  const float* wq = (const float*)d_in[1];
  const float* bq = (const float*)d_in[2];
  const float* wk = (const float*)d_in[3];
  const float* bk = (const float*)d_in[4];
  const float* wv = (const float*)d_in[5];
  const float* bv = (const float*)d_in[6];
  const float* wo = (const float*)d_in[7];
  const float* bo = (const float*)d_in[8];

  char* ws = (char*)d_ws;
  const size_t XB = (size_t)MROWS * HIDDEN * 2;   // 16 MiB
  const size_t WB = (size_t)HIDDEN * HIDDEN * 2;  // 2 MiB
  unsigned short* xb  = (unsigned short*)(ws);
  unsigned short* wqt = (unsigned short*)(ws + XB);            // wq^T | wk^T contiguous
  unsigned short* wkt = (unsigned short*)(ws + XB + WB);
  unsigned short* wvt = (unsigned short*)(ws + XB + 2 * WB);
  unsigned short* wot = (unsigned short*)(ws + XB + 3 * WB);
  unsigned short* Qb  = (unsigned short*)(ws + XB + 4 * WB);
  unsigned short* Kb  = (unsigned short*)(ws + 2 * XB + 4 * WB);
  _Float16*       Vtb = (_Float16*)      (ws + 3 * XB + 4 * WB);
  unsigned short* Mg  = (unsigned short*)(ws + 4 * XB + 4 * WB);

  // 1. merged prep: transpose+cast weights (blocks 0-1023) + cast x (blocks 1024-3071)
  prep_kernel<<<dim3(3072), 256, 0, stream>>>(
      x, wq, wk, wv, wo, xb, wqt, wkt, wvt, wot);

  // 2. fused QKV projections, BK=32 TRIPLE-buffer depth-2 (this round's single variable).
  //    Q folded with log2(e)/sqrt(1024).
  const float SQSCALE = 1.44269504088896f / 32.0f;
  gemm_qkv256_kernel<<<dim3(768), 512, 0, stream>>>(
      xb, wqt, wvt, bq, bk, bv, Qb, Kb, Vtb, SQSCALE);

  // 3. attention v9 (proven, frozen)
  attn_kernel<<<dim3(SEQ / 256 * NHEADS * BATCH), 256, 0, stream>>>(Qb, Kb, Vtb, Mg);

  // 4. output projection -> fp32 d_out, 128x128 tiles, 512 blocks = 2 blocks/CU co-resident
  gemm_out256_kernel<<<dim3(512), 512, 0, stream>>>(Mg, wot, bo, (float*)d_out);
}